// Round 6
// baseline (717.717 us; speedup 1.0000x reference)
//
#include <hip/hip_runtime.h>
#include <hip/hip_bf16.h>

// ---------------------------------------------------------------------------
// InvariantPolynomial, round 6.
//  vs R5 (passed, 561 us):
//   * k_mid: rewritten per-edge direct contraction using the k_out-verified
//     skeleton: wave/node, wave-uniform loads, g[51] in registers (uniform
//     across lanes), cndmask selects for lane-varying g components. No LDS
//     atomics, no G tensor, no staging. Decode/fold tables line-verified
//     against R2's passing phase-2.  Output mid stored as bf16.
//   * k_out: identical verified logic, mid reads switched to bf16 (row 736 B,
//     halves the scattered gather traffic).
//
// ws layout:
//   counts  @ int   [0      , 20000)
//   start   @ int   [32768  , 52769)
//   cursor  @ int   [65536  , 85536)
//   csr     @ int   [98304  , 418304)
//   node_sh @ float [524288 , 704288)      20000 x 9  (pre-scaled by inv_nn)
//   mid16   @ bf16  [byte 4194304, +14.72MB) 20000 x 368
// ---------------------------------------------------------------------------

#define N_EDGES   320000
#define NN_NODES  20000
#define NN_GRAPHS 5000

__device__ __forceinline__ void sh_from_vec(float x, float y, float z,
                                            float* B1, float* B2) {
    const float s3   = 1.7320508075688772f;
    const float s15  = 3.8729833462074170f;
    const float s5h  = 1.1180339887498949f;
    const float s15h = 1.9364916731037085f;
    B1[0] = s3 * y; B1[1] = s3 * z; B1[2] = s3 * x;
    float r2 = x * x + y * y + z * z;
    B2[0] = s15 * x * y;
    B2[1] = s15 * y * z;
    B2[2] = s5h * (3.f * z * z - r2);
    B2[3] = s15 * x * z;
    B2[4] = s15h * (x * x - y * y);
}

__device__ __forceinline__ float sel3(int k, float a, float b, float c) {
    return k == 0 ? a : (k == 1 ? b : c);
}
__device__ __forceinline__ float sel5(int k, float a, float b, float c,
                                      float d, float e) {
    return k == 0 ? a : (k == 1 ? b : (k == 2 ? c : (k == 3 ? d : e)));
}

// Compute the 51-dim geometric vector g (all-constant indexing -> registers).
__device__ __forceinline__ void compute_g(float a0, const float* A1, const float* A2,
                                          const float* B1, const float* B2,
                                          float* g) {
    const float r3  = 0.57735026918962576f;
    const float r5  = 0.44721359549995794f;
    const float r6  = 0.40824829046386302f;
    const float r10 = 0.31622776601683794f;
    const float s30 = 0.18257418583505536f;
    const float rt3 = 1.7320508075688772f;
    const float c222 = 0.58554004376911990f;
    const float q6 = 0.40824829046386302f;
    const float h6 = 0.20412414523193151f;
    const float h2 = 0.35355339059327376f;
    const float r2c = 0.70710678118654752f;

    g[0] = a0;
    g[1] = a0 * B1[0] * r3;
    g[2] = a0 * B1[1] * r3;
    g[3] = a0 * B1[2] * r3;
    g[4] = a0 * B2[0] * r5;
    g[5] = a0 * B2[1] * r5;
    g[6] = a0 * B2[2] * r5;
    g[7] = a0 * B2[3] * r5;
    g[8] = a0 * B2[4] * r5;
    g[9]  = A1[0] * r3;
    g[10] = A1[1] * r3;
    g[11] = A1[2] * r3;
    g[12] = -r3 * (A1[0] * B1[0] + A1[1] * B1[1] + A1[2] * B1[2]);
    g[13] = -r6 * (A1[1] * B1[2] - A1[2] * B1[1]);
    g[14] = -r6 * (A1[2] * B1[0] - A1[0] * B1[2]);
    g[15] = -r6 * (A1[0] * B1[1] - A1[1] * B1[0]);
    g[16] = r10 * (A1[0] * B1[2] + A1[2] * B1[0]);
    g[17] = r10 * (A1[0] * B1[1] + A1[1] * B1[0]);
    g[18] = s30 * (2.f * A1[1] * B1[1] - A1[0] * B1[0] - A1[2] * B1[2]);
    g[19] = r10 * (A1[1] * B1[2] + A1[2] * B1[1]);
    g[20] = r10 * (A1[2] * B1[2] - A1[0] * B1[0]);
    {
        float Byy = -B2[2] * q6 - B2[4] * r2c;
        float Bzz = 2.f * B2[2] * q6;
        float Bxx = -B2[2] * q6 + B2[4] * r2c;
        float Bxy = B2[0] * r2c;
        float Byz = B2[1] * r2c;
        float Bxz = B2[3] * r2c;
        g[21] = -r5 * (Byy * A1[0] + Byz * A1[1] + Bxy * A1[2]);
        g[22] = -r5 * (Byz * A1[0] + Bzz * A1[1] + Bxz * A1[2]);
        g[23] = -r5 * (Bxy * A1[0] + Bxz * A1[1] + Bxx * A1[2]);
    }
    g[24] = -s30 * (B2[1] * A1[0] - B2[3] * A1[2] + 2.f * B2[4] * A1[1]);
    g[25] = -s30 * (-B2[0] * A1[0] - rt3 * B2[2] * A1[2] + B2[3] * A1[1] - B2[4] * A1[2]);
    g[26] = -s30 * (rt3 * B2[1] * A1[2] - rt3 * B2[3] * A1[0]);
    g[27] = -s30 * (B2[0] * A1[2] - B2[1] * A1[1] + rt3 * B2[2] * A1[0] - B2[4] * A1[0]);
    g[28] = -s30 * (-2.f * B2[0] * A1[1] + B2[1] * A1[2] + B2[3] * A1[0]);
    g[29] = A2[0] * r5;
    g[30] = A2[1] * r5;
    g[31] = A2[2] * r5;
    g[32] = A2[3] * r5;
    g[33] = A2[4] * r5;
    {
        float Ayy = -A2[2] * q6 - A2[4] * r2c;
        float Azz = 2.f * A2[2] * q6;
        float Axx = -A2[2] * q6 + A2[4] * r2c;
        float Axy = A2[0] * r2c;
        float Ayz = A2[1] * r2c;
        float Axz = A2[3] * r2c;
        g[34] = -r5 * (Ayy * B1[0] + Ayz * B1[1] + Axy * B1[2]);
        g[35] = -r5 * (Ayz * B1[0] + Azz * B1[1] + Axz * B1[2]);
        g[36] = -r5 * (Axy * B1[0] + Axz * B1[1] + Axx * B1[2]);
    }
    g[37] = s30 * (A2[1] * B1[0] - A2[3] * B1[2] + 2.f * A2[4] * B1[1]);
    g[38] = s30 * (-A2[0] * B1[0] - rt3 * A2[2] * B1[2] + A2[3] * B1[1] - A2[4] * B1[2]);
    g[39] = s30 * (rt3 * A2[1] * B1[2] - rt3 * A2[3] * B1[0]);
    g[40] = s30 * (A2[0] * B1[2] - A2[1] * B1[1] + rt3 * A2[2] * B1[0] - A2[4] * B1[0]);
    g[41] = s30 * (-2.f * A2[0] * B1[1] + A2[1] * B1[2] + A2[3] * B1[0]);
    g[42] = r5 * (A2[0] * B2[0] + A2[1] * B2[1] + A2[2] * B2[2] +
                  A2[3] * B2[3] + A2[4] * B2[4]);
    g[43] = s30 * (-A2[0] * B2[1] + A2[1] * B2[0] +
                   rt3 * (A2[2] * B2[3] - A2[3] * B2[2]) +
                   A2[3] * B2[4] - A2[4] * B2[3]);
    g[44] = s30 * (-2.f * A2[0] * B2[4] + 2.f * A2[4] * B2[0] -
                   A2[1] * B2[3] + A2[3] * B2[1]);
    g[45] = s30 * (A2[0] * B2[3] - A2[3] * B2[0] +
                   rt3 * (A2[1] * B2[2] - A2[2] * B2[1]) +
                   A2[1] * B2[4] - A2[4] * B2[1]);
    g[46] = -c222 * (-q6 * (A2[0] * B2[2] + A2[2] * B2[0]) +
                     h2 * (A2[1] * B2[3] + A2[3] * B2[1]));
    g[47] = -c222 * (h6 * (A2[1] * B2[2] + A2[2] * B2[1]) -
                     h2 * (A2[1] * B2[4] + A2[4] * B2[1]) +
                     h2 * (A2[0] * B2[3] + A2[3] * B2[0]));
    g[48] = -c222 * (q6 * (A2[2] * B2[2] - A2[0] * B2[0] - A2[4] * B2[4]) +
                     h6 * (A2[1] * B2[1] + A2[3] * B2[3]));
    g[49] = -c222 * (h6 * (A2[3] * B2[2] + A2[2] * B2[3]) +
                     h2 * (A2[3] * B2[4] + A2[4] * B2[3]) +
                     h2 * (A2[0] * B2[1] + A2[1] * B2[0]));
    g[50] = -c222 * (-q6 * (A2[4] * B2[2] + A2[2] * B2[4]) +
                     h2 * (A2[3] * B2[3] - A2[1] * B2[1]));
}

// --------------------------- zero ------------------------------------------
__global__ __launch_bounds__(256) void k_zero(int* __restrict__ counts,
                                              float* __restrict__ out) {
    int tid = blockIdx.x * blockDim.x + threadIdx.x;
    int stride = gridDim.x * blockDim.x;
    for (int i = tid; i < NN_NODES; i += stride) counts[i] = 0;
    for (int i = tid; i < NN_GRAPHS * 7; i += stride) out[i] = 0.f;
}

// --------------------------- histogram -------------------------------------
__global__ __launch_bounds__(256) void k_hist(const int* __restrict__ edst,
                                              int* __restrict__ counts) {
    int e = blockIdx.x * blockDim.x + threadIdx.x;
    if (e < N_EDGES) atomicAdd(&counts[edst[e]], 1);
}

// --------------------------- exclusive scan (1 block of 1024) --------------
__global__ __launch_bounds__(1024) void k_scan(const int* __restrict__ counts,
                                               int* __restrict__ start,
                                               int* __restrict__ cursor) {
    __shared__ int sdata[1024];
    __shared__ int carry;
    int tid = threadIdx.x;
    if (tid == 0) carry = 0;
    __syncthreads();
    for (int base = 0; base < NN_NODES; base += 1024) {
        int i = base + tid;
        int v = (i < NN_NODES) ? counts[i] : 0;
        sdata[tid] = v;
        __syncthreads();
        for (int off = 1; off < 1024; off <<= 1) {
            int t = (tid >= off) ? sdata[tid - off] : 0;
            __syncthreads();
            sdata[tid] += t;
            __syncthreads();
        }
        int incl = sdata[tid];
        int c = carry;
        if (i < NN_NODES) {
            int excl = c + incl - v;
            start[i] = excl;
            cursor[i] = excl;
        }
        __syncthreads();
        if (tid == 0) carry = c + sdata[1023];
        __syncthreads();
    }
    if (tid == 0) start[NN_NODES] = carry;   // = N_EDGES
}

// --------------------------- CSR fill --------------------------------------
__global__ __launch_bounds__(256) void k_fill(const int* __restrict__ esrc,
                                              const int* __restrict__ edst,
                                              const int* __restrict__ zarr,
                                              int* __restrict__ cursor,
                                              int* __restrict__ csr) {
    int e = blockIdx.x * blockDim.x + threadIdx.x;
    if (e >= N_EDGES) return;
    int d = edst[e];
    int s = esrc[e];
    int q = 4 * zarr[s] + zarr[d];
    int p = atomicAdd(&cursor[d], 1);
    csr[p] = s | (q << 16);
}

// --------------------------- node_sh gather (wave per node) ----------------
__global__ __launch_bounds__(256) void k_nodesh(const float* __restrict__ pos,
                                                const int* __restrict__ start,
                                                const int* __restrict__ csr,
                                                float* __restrict__ node_sh) {
    int wave = threadIdx.x >> 6;
    int lane = threadIdx.x & 63;
    int n = blockIdx.x * 4 + wave;
    if (n >= NN_NODES) return;
    float pdx = pos[3 * n], pdy = pos[3 * n + 1], pdz = pos[3 * n + 2];
    int s0 = start[n], s1 = start[n + 1];
    float acc[9] = {0.f, 0.f, 0.f, 0.f, 0.f, 0.f, 0.f, 0.f, 0.f};
    for (int idx = s0 + lane; idx < s1; idx += 64) {
        int s = csr[idx] & 0xFFFF;
        float x = pos[3 * s] - pdx;
        float y = pos[3 * s + 1] - pdy;
        float z = pos[3 * s + 2] - pdz;
        float B1[3], B2[5];
        sh_from_vec(x, y, z, B1, B2);
        acc[0] += 1.f;
        acc[1] += B1[0]; acc[2] += B1[1]; acc[3] += B1[2];
        acc[4] += B2[0]; acc[5] += B2[1]; acc[6] += B2[2];
        acc[7] += B2[3]; acc[8] += B2[4];
    }
#pragma unroll
    for (int off = 32; off > 0; off >>= 1)
#pragma unroll
        for (int i = 0; i < 9; i++) acc[i] += __shfl_down(acc[i], off, 64);
    if (lane == 0) {
        const float inv_nn = 0.57735026918962576f;
#pragma unroll
        for (int i = 0; i < 9; i++) node_sh[n * 9 + i] = acc[i] * inv_nn;
    }
}

// --------------- fused TP1, per-edge direct (k_out-style skeleton) ---------
// wave per node; wave-uniform loads; g in registers (uniform across lanes);
// lane j-ownership j = lane + 64k with cndmask selects. Alpha folded into W1.
__global__ __launch_bounds__(256) void k_mid(const float* __restrict__ pos,
                                             const float* __restrict__ node_sh,
                                             const int* __restrict__ start,
                                             const int* __restrict__ csr,
                                             const float* __restrict__ w1,
                                             __hip_bfloat16* __restrict__ mid16) {
    __shared__ float lw[6912];
    {
        // region coefficient fold (alpha_c * 4 * inv_nn) — verified table
        const int   rs[16] = {0, 1024, 1408, 1664, 2048, 3072, 3456, 3712,
                              4096, 4352, 4608, 4992, 5248, 6272, 6656, 6912};
        const float rc[15] = {0.33333333333333333f, 0.5f, 0.64549722436790280f,
                              0.5f, 0.33333333333333333f, 0.70710678118654752f,
                              0.64549722436790280f, 0.5f, 0.91287092917527690f,
                              0.64549722436790280f, 0.5f, 0.91287092917527690f,
                              0.33333333333333333f, 0.70710678118654752f,
                              0.64549722436790280f};
        for (int i = threadIdx.x; i < 6912; i += 256) {
            float c = 0.f;
#pragma unroll
            for (int r = 0; r < 15; r++)
                if (i >= rs[r] && i < rs[r + 1]) c = rc[r];
            lw[i] = w1[i] * c;
        }
    }
    __syncthreads();

    int wave = threadIdx.x >> 6;
    int lane = threadIdx.x & 63;
    int n = blockIdx.x * 4 + wave;
    float pdx = pos[3 * n], pdy = pos[3 * n + 1], pdz = pos[3 * n + 2];
    int s0 = start[n], s1 = start[n + 1];

    float acc0 = 0.f, acc1 = 0.f, acc2 = 0.f, acc3 = 0.f, acc4 = 0.f, acc5 = 0.f;
    // per-lane decode (line-verified against R2 phase-2 j-mapping)
    int t1 = lane;           int w1i = t1 / 3, k1i = t1 - 3 * w1i;
    int t2 = (lane < 8) ? (64 + lane) : (lane - 8);
    int w2i = t2 / 3, k2i = t2 - 3 * w2i;
    int t3 = (lane < 16) ? (56 + lane) : (lane - 16);
    int K3 = (lane < 16) ? 3 : 5;
    int w3i = t3 / K3, k3i = t3 - K3 * w3i;
    int t4 = (lane < 32) ? (48 + lane) : (lane - 32);
    int w4i = t4 / 5, k4i = t4 - 5 * w4i;
    int t5 = 32 + lane;      int w5i = t5 / 5, k5i = t5 - 5 * w5i;
    if (w5i > 15) w5i = 15;  // lanes>=48 don't store acc5; clamp index

    for (int idx = s0; idx < s1; ++idx) {
        int pk = csr[idx];               // wave-uniform address load
        int s = pk & 0xFFFF;
        int q = pk >> 16;
        float x = pos[3 * s] - pdx;
        float y = pos[3 * s + 1] - pdy;
        float z = pos[3 * s + 2] - pdz;
        float B1[3], B2[5];
        sh_from_vec(x, y, z, B1, B2);
        const float* nr = node_sh + s * 9;   // pre-scaled by inv_nn
        float a0 = nr[0];
        float A1v[3] = {nr[1], nr[2], nr[3]};
        float A2v[5] = {nr[4], nr[5], nr[6], nr[7], nr[8]};
        float g[51];
        compute_g(a0, A1v, A2v, B1, B2, g);

        int q64 = q * 64, q24 = q * 24, q16 = q * 16;
        // k=0: c0, w=lane
        acc0 += g[0]  * lw[q64 + lane]
              + g[12] * lw[2048 + q64 + lane]
              + g[42] * lw[5248 + q64 + lane];
        // k=1: c1
        acc1 += sel3(k1i, g[13], g[14], g[15]) * lw[3072 + q24 + w1i]
              + sel3(k1i, g[43], g[44], g[45]) * lw[6272 + q24 + w1i];
        // k=2: c1 (lane<8) / c2
        if (lane < 8) {
            acc2 += sel3(k2i, g[13], g[14], g[15]) * lw[3072 + q24 + w2i]
                  + sel3(k2i, g[43], g[44], g[45]) * lw[6272 + q24 + w2i];
        } else {
            acc2 += sel3(k2i, g[1],  g[2],  g[3])  * lw[1024 + q24 + w2i]
                  + sel3(k2i, g[9],  g[10], g[11]) * lw[1664 + q24 + w2i]
                  + sel3(k2i, g[21], g[22], g[23]) * lw[3712 + q24 + w2i]
                  + sel3(k2i, g[34], g[35], g[36]) * lw[4608 + q24 + w2i];
        }
        // k=3: c2 (lane<16) / c3
        if (lane < 16) {
            acc3 += sel3(k3i, g[1],  g[2],  g[3])  * lw[1024 + q24 + w3i]
                  + sel3(k3i, g[9],  g[10], g[11]) * lw[1664 + q24 + w3i]
                  + sel3(k3i, g[21], g[22], g[23]) * lw[3712 + q24 + w3i]
                  + sel3(k3i, g[34], g[35], g[36]) * lw[4608 + q24 + w3i];
        } else {
            acc3 += sel5(k3i, g[4],  g[5],  g[6],  g[7],  g[8])  * lw[1408 + q16 + w3i]
                  + sel5(k3i, g[16], g[17], g[18], g[19], g[20]) * lw[3456 + q16 + w3i]
                  + sel5(k3i, g[29], g[30], g[31], g[32], g[33]) * lw[4352 + q16 + w3i]
                  + sel5(k3i, g[46], g[47], g[48], g[49], g[50]) * lw[6656 + q16 + w3i];
        }
        // k=4: c3 (lane<32) / c4
        if (lane < 32) {
            acc4 += sel5(k4i, g[4],  g[5],  g[6],  g[7],  g[8])  * lw[1408 + q16 + w4i]
                  + sel5(k4i, g[16], g[17], g[18], g[19], g[20]) * lw[3456 + q16 + w4i]
                  + sel5(k4i, g[29], g[30], g[31], g[32], g[33]) * lw[4352 + q16 + w4i]
                  + sel5(k4i, g[46], g[47], g[48], g[49], g[50]) * lw[6656 + q16 + w4i];
        } else {
            acc4 += sel5(k4i, g[24], g[25], g[26], g[27], g[28]) * lw[4096 + q16 + w4i]
                  + sel5(k4i, g[37], g[38], g[39], g[40], g[41]) * lw[4992 + q16 + w4i];
        }
        // k=5: c4 (stored only for lane<48)
        acc5 += sel5(k5i, g[24], g[25], g[26], g[27], g[28]) * lw[4096 + q16 + w5i]
              + sel5(k5i, g[37], g[38], g[39], g[40], g[41]) * lw[4992 + q16 + w5i];
    }
    __hip_bfloat16* mrow = mid16 + (size_t)n * 368;
    mrow[lane]       = __float2bfloat16(acc0);
    mrow[64 + lane]  = __float2bfloat16(acc1);
    mrow[128 + lane] = __float2bfloat16(acc2);
    mrow[192 + lane] = __float2bfloat16(acc3);
    mrow[256 + lane] = __float2bfloat16(acc4);
    if (lane < 48) mrow[320 + lane] = __float2bfloat16(acc5);
}

// --------------- fused TP2 + graph reduce (wave per node) ------------------
// R5-verified logic; mid reads now bf16.
__global__ __launch_bounds__(512) void k_out(const float* __restrict__ pos,
                                             const int* __restrict__ batch,
                                             const int* __restrict__ start,
                                             const int* __restrict__ csr,
                                             const __hip_bfloat16* __restrict__ mid16,
                                             const float* __restrict__ w2,
                                             float* __restrict__ out) {
    __shared__ float lw2[10624];
    {
        const float cT0f =  0.02830690f;
        const float cT1f = -0.02635231f;
        const float cT2f = -0.01634300f;
        const float cT3f =  0.01265893f;
        const float cT4f =  0.02041241f;
        for (int i = threadIdx.x; i < 10624; i += 512) {
            int src; float c;
            if (i < 6144) {            // T0 [w][q][u] <- (u*16+q)*6+w
                int w = i / 1024, r = i - 1024 * w;
                int q = r / 64, u = r - 64 * q;
                src = (u * 16 + q) * 6 + w; c = cT0f;
            } else if (i < 6528) {     // T1 [q][u]
                int t = i - 6144; int q = t / 24, u = t - 24 * q;
                src = 6144 + u * 16 + q; c = cT1f;
            } else if (i < 8832) {     // T2 [w][q][u]
                int t = i - 6528; int w = t / 384, r = t - 384 * w;
                int q = r / 24, u = r - 24 * q;
                src = 6528 + (u * 16 + q) * 6 + w; c = cT2f;
            } else if (i < 10368) {    // T3 [w][q][u]
                int t = i - 8832; int w = t / 256, r = t - 256 * w;
                int q = r / 16, u = r - 16 * q;
                src = 8832 + (u * 16 + q) * 6 + w; c = cT3f;
            } else {                   // T4 [q][u]
                int t = i - 10368; int q = t / 16, u = t - 16 * q;
                src = 10368 + u * 16 + q; c = cT4f;
            }
            lw2[i] = w2[src] * c;
        }
    }
    __syncthreads();

    int wave = threadIdx.x >> 6;
    int lane = threadIdx.x & 63;
    int n = blockIdx.x * 8 + wave;
    float pdx = pos[3 * n], pdy = pos[3 * n + 1], pdz = pos[3 * n + 2];
    int s0 = start[n], s1 = start[n + 1];

    float p0[6] = {0.f, 0.f, 0.f, 0.f, 0.f, 0.f};   // T0, u = lane
    float pA[6] = {0.f, 0.f, 0.f, 0.f, 0.f, 0.f};   // T1/T2/T3 by lane range
    float pB = 0.f;                                  // T4, lanes 0..15

    for (int idx = s0; idx < s1; ++idx) {
        int pk = csr[idx];
        int s = pk & 0xFFFF;
        int q = pk >> 16;
        float x = pos[3 * s] - pdx;
        float y = pos[3 * s + 1] - pdy;
        float z = pos[3 * s + 2] - pdz;
        float B1[3], B2[5];
        sh_from_vec(x, y, z, B1, B2);
        const __hip_bfloat16* mrow = mid16 + (size_t)s * 368;
        int q64 = q * 64, q24 = q * 24, q16 = q * 16;

        // T0: u = lane; weights [w][q][u] stride-1 in lane
        {
            float m = __bfloat162float(mrow[lane]);
#pragma unroll
            for (int w = 0; w < 6; w++) p0[w] += m * lw2[w * 1024 + q64 + lane];
        }
        if (lane < 24) {            // T1
            const __hip_bfloat16* rp = mrow + 64 + 3 * lane;
            float dd = __bfloat162float(rp[0]) * B1[0] +
                       __bfloat162float(rp[1]) * B1[1] +
                       __bfloat162float(rp[2]) * B1[2];
            pA[0] += dd * lw2[6144 + q24 + lane];
        } else if (lane < 48) {     // T2
            int u = lane - 24;
            const __hip_bfloat16* rp = mrow + 136 + 3 * u;
            float dd = __bfloat162float(rp[0]) * B1[0] +
                       __bfloat162float(rp[1]) * B1[1] +
                       __bfloat162float(rp[2]) * B1[2];
#pragma unroll
            for (int w = 0; w < 6; w++) pA[w] += dd * lw2[6528 + w * 384 + q24 + u];
        } else {                    // T3
            int u = lane - 48;
            const __hip_bfloat16* rp = mrow + 208 + 5 * u;
            float dd = __bfloat162float(rp[0]) * B2[0] +
                       __bfloat162float(rp[1]) * B2[1] +
                       __bfloat162float(rp[2]) * B2[2] +
                       __bfloat162float(rp[3]) * B2[3] +
                       __bfloat162float(rp[4]) * B2[4];
#pragma unroll
            for (int w = 0; w < 6; w++) pA[w] += dd * lw2[8832 + w * 256 + q16 + u];
        }
        if (lane < 16) {            // T4
            const __hip_bfloat16* rp = mrow + 288 + 5 * lane;
            float dd = __bfloat162float(rp[0]) * B2[0] +
                       __bfloat162float(rp[1]) * B2[1] +
                       __bfloat162float(rp[2]) * B2[2] +
                       __bfloat162float(rp[3]) * B2[3] +
                       __bfloat162float(rp[4]) * B2[4];
            pB += dd * lw2[10368 + q16 + lane];
        }
    }

    float o0 = 0.f;
    float ov[6];
#pragma unroll
    for (int w = 0; w < 6; w++) ov[w] = p0[w];
    if (lane < 24) {
        o0 += pA[0];
    } else {
#pragma unroll
        for (int w = 0; w < 6; w++) ov[w] += pA[w];
    }
    if (lane < 16) o0 += pB;

#pragma unroll
    for (int off = 32; off > 0; off >>= 1) {
        o0 += __shfl_down(o0, off, 64);
#pragma unroll
        for (int w = 0; w < 6; w++) ov[w] += __shfl_down(ov[w], off, 64);
    }
    if (lane == 0) {
        float* og = out + batch[n] * 7;
        atomicAdd(og + 0, o0);
#pragma unroll
        for (int w = 0; w < 6; w++) atomicAdd(og + 1 + w, ov[w]);
    }
}

// ---------------------------------------------------------------------------
extern "C" void kernel_launch(void* const* d_in, const int* in_sizes, int n_in,
                              void* d_out, int out_size, void* d_ws, size_t ws_size,
                              hipStream_t stream) {
    const float* pos  = (const float*)d_in[0];
    const int*   z    = (const int*)d_in[1];
    const int*   bat  = (const int*)d_in[2];
    const int*   esrc = (const int*)d_in[3];
    const int*   edst = (const int*)d_in[4];
    const float* w1   = (const float*)d_in[5];
    const float* w2   = (const float*)d_in[6];
    float* out = (float*)d_out;

    int*   wsI = (int*)d_ws;
    float* wsF = (float*)d_ws;
    int* counts = wsI + 0;
    int* start  = wsI + 32768;
    int* cursor = wsI + 65536;
    int* csr    = wsI + 98304;
    float* node_sh = wsF + 524288;
    __hip_bfloat16* mid16 = (__hip_bfloat16*)(wsF + 1048576);

    k_zero<<<64, 256, 0, stream>>>(counts, out);
    k_hist<<<(N_EDGES + 255) / 256, 256, 0, stream>>>(edst, counts);
    k_scan<<<1, 1024, 0, stream>>>(counts, start, cursor);
    k_fill<<<(N_EDGES + 255) / 256, 256, 0, stream>>>(esrc, edst, z, cursor, csr);
    k_nodesh<<<NN_NODES / 4, 256, 0, stream>>>(pos, start, csr, node_sh);
    k_mid<<<NN_NODES / 4, 256, 0, stream>>>(pos, node_sh, start, csr, w1, mid16);
    k_out<<<NN_NODES / 8, 512, 0, stream>>>(pos, bat, start, csr, mid16, w2, out);
}

// Round 7
// 552.308 us; speedup vs baseline: 1.2995x; 1.2995x over previous
//
#include <hip/hip_runtime.h>
#include <hip/hip_bf16.h>

// ---------------------------------------------------------------------------
// InvariantPolynomial, round 7 — all-verified composition:
//   * k_mid : R2/R5-verified LDS-G version (G[8][816] in LDS, ds-atomics,
//             phase-2 W1 contraction), single change: mid stored as bf16.
//   * k_out : R6-verified permuted-LDS W2 + bf16 mid gather.
//   * scan  : R2-verified naive single-block scan (shuffle scan quarantined).
//
// ws layout:
//   counts  @ int   [0      , 20000)
//   start   @ int   [32768  , 52769)
//   cursor  @ int   [65536  , 85536)
//   csr     @ int   [98304  , 418304)
//   node_sh @ float [524288 , 704288)       20000 x 9  (pre-scaled by inv_nn)
//   mid16   @ bf16  [byte 4194304, +14.72MB) 20000 x 368
// ---------------------------------------------------------------------------

#define N_EDGES   320000
#define NN_NODES  20000
#define NN_GRAPHS 5000

__device__ __forceinline__ void sh_from_vec(float x, float y, float z,
                                            float* B1, float* B2) {
    const float s3   = 1.7320508075688772f;
    const float s15  = 3.8729833462074170f;
    const float s5h  = 1.1180339887498949f;
    const float s15h = 1.9364916731037085f;
    B1[0] = s3 * y; B1[1] = s3 * z; B1[2] = s3 * x;
    float r2 = x * x + y * y + z * z;
    B2[0] = s15 * x * y;
    B2[1] = s15 * y * z;
    B2[2] = s5h * (3.f * z * z - r2);
    B2[3] = s15 * x * z;
    B2[4] = s15h * (x * x - y * y);
}

// --------------------------- zero ------------------------------------------
__global__ __launch_bounds__(256) void k_zero(int* __restrict__ counts,
                                              float* __restrict__ out) {
    int tid = blockIdx.x * blockDim.x + threadIdx.x;
    int stride = gridDim.x * blockDim.x;
    for (int i = tid; i < NN_NODES; i += stride) counts[i] = 0;
    for (int i = tid; i < NN_GRAPHS * 7; i += stride) out[i] = 0.f;
}

// --------------------------- histogram -------------------------------------
__global__ __launch_bounds__(256) void k_hist(const int* __restrict__ edst,
                                              int* __restrict__ counts) {
    int e = blockIdx.x * blockDim.x + threadIdx.x;
    if (e < N_EDGES) atomicAdd(&counts[edst[e]], 1);
}

// --------------------------- exclusive scan (1 block of 1024) --------------
__global__ __launch_bounds__(1024) void k_scan(const int* __restrict__ counts,
                                               int* __restrict__ start,
                                               int* __restrict__ cursor) {
    __shared__ int sdata[1024];
    __shared__ int carry;
    int tid = threadIdx.x;
    if (tid == 0) carry = 0;
    __syncthreads();
    for (int base = 0; base < NN_NODES; base += 1024) {
        int i = base + tid;
        int v = (i < NN_NODES) ? counts[i] : 0;
        sdata[tid] = v;
        __syncthreads();
        for (int off = 1; off < 1024; off <<= 1) {
            int t = (tid >= off) ? sdata[tid - off] : 0;
            __syncthreads();
            sdata[tid] += t;
            __syncthreads();
        }
        int incl = sdata[tid];
        int c = carry;
        if (i < NN_NODES) {
            int excl = c + incl - v;
            start[i] = excl;
            cursor[i] = excl;
        }
        __syncthreads();
        if (tid == 0) carry = c + sdata[1023];
        __syncthreads();
    }
    if (tid == 0) start[NN_NODES] = carry;   // = N_EDGES
}

// --------------------------- CSR fill --------------------------------------
__global__ __launch_bounds__(256) void k_fill(const int* __restrict__ esrc,
                                              const int* __restrict__ edst,
                                              const int* __restrict__ zarr,
                                              int* __restrict__ cursor,
                                              int* __restrict__ csr) {
    int e = blockIdx.x * blockDim.x + threadIdx.x;
    if (e >= N_EDGES) return;
    int d = edst[e];
    int s = esrc[e];
    int q = 4 * zarr[s] + zarr[d];
    int p = atomicAdd(&cursor[d], 1);
    csr[p] = s | (q << 16);
}

// --------------------------- node_sh gather (wave per node) ----------------
__global__ __launch_bounds__(256) void k_nodesh(const float* __restrict__ pos,
                                                const int* __restrict__ start,
                                                const int* __restrict__ csr,
                                                float* __restrict__ node_sh) {
    int wave = threadIdx.x >> 6;
    int lane = threadIdx.x & 63;
    int n = blockIdx.x * 4 + wave;
    if (n >= NN_NODES) return;
    float pdx = pos[3 * n], pdy = pos[3 * n + 1], pdz = pos[3 * n + 2];
    int s0 = start[n], s1 = start[n + 1];
    float acc[9] = {0.f, 0.f, 0.f, 0.f, 0.f, 0.f, 0.f, 0.f, 0.f};
    for (int idx = s0 + lane; idx < s1; idx += 64) {
        int s = csr[idx] & 0xFFFF;
        float x = pos[3 * s] - pdx;
        float y = pos[3 * s + 1] - pdy;
        float z = pos[3 * s + 2] - pdz;
        float B1[3], B2[5];
        sh_from_vec(x, y, z, B1, B2);
        acc[0] += 1.f;
        acc[1] += B1[0]; acc[2] += B1[1]; acc[3] += B1[2];
        acc[4] += B2[0]; acc[5] += B2[1]; acc[6] += B2[2];
        acc[7] += B2[3]; acc[8] += B2[4];
    }
#pragma unroll
    for (int off = 32; off > 0; off >>= 1)
#pragma unroll
        for (int i = 0; i < 9; i++) acc[i] += __shfl_down(acc[i], off, 64);
    if (lane == 0) {
        const float inv_nn = 0.57735026918962576f;
#pragma unroll
        for (int i = 0; i < 9; i++) node_sh[n * 9 + i] = acc[i] * inv_nn;
    }
}

// --------------- fused TP1: G in LDS -> W1 contraction -> mid (bf16) -------
// (R2/R5-verified; only change: bf16 stores)
__global__ __launch_bounds__(384) void k_mid(const float* __restrict__ pos,
                                             const float* __restrict__ node_sh,
                                             const int* __restrict__ start,
                                             const int* __restrict__ csr,
                                             const float* __restrict__ w1,
                                             __hip_bfloat16* __restrict__ mid16) {
    __shared__ float lw[6912];
    __shared__ float Gl[8 * 816];
    int t = threadIdx.x;
    for (int i = t; i < 6912; i += 384) lw[i] = w1[i];
    for (int i = t; i < 8 * 816; i += 384) Gl[i] = 0.f;
    __syncthreads();

    int r = t / 48;
    int slot = t - 48 * r;
    int n = blockIdx.x * 8 + r;
    float pdx = pos[3 * n], pdy = pos[3 * n + 1], pdz = pos[3 * n + 2];
    int s0 = start[n], s1 = start[n + 1];
    float* Gb = Gl + r * 816;

    const float r3  = 0.57735026918962576f;
    const float r5  = 0.44721359549995794f;
    const float r6  = 0.40824829046386302f;
    const float r10 = 0.31622776601683794f;
    const float s30 = 0.18257418583505536f;
    const float rt3 = 1.7320508075688772f;
    const float c222 = 0.58554004376911990f;
    const float q6 = 0.40824829046386302f;
    const float h6 = 0.20412414523193151f;
    const float h2 = 0.35355339059327376f;
    const float r2c = 0.70710678118654752f;

    for (int idx = s0 + slot; idx < s1; idx += 48) {
        int pk = csr[idx];
        int s = pk & 0xFFFF;
        int q = pk >> 16;
        float x = pos[3 * s] - pdx;
        float y = pos[3 * s + 1] - pdy;
        float z = pos[3 * s + 2] - pdz;
        float B1[3], B2[5];
        sh_from_vec(x, y, z, B1, B2);
        const float* nr = node_sh + s * 9;      // pre-scaled by inv_nn
        float a0 = nr[0];
        float A1[3] = {nr[1], nr[2], nr[3]};
        float A2[5] = {nr[4], nr[5], nr[6], nr[7], nr[8]};
        float* gr = Gb + q * 51;

        atomicAdd(gr + 0, a0);
        atomicAdd(gr + 1, a0 * B1[0] * r3);
        atomicAdd(gr + 2, a0 * B1[1] * r3);
        atomicAdd(gr + 3, a0 * B1[2] * r3);
        atomicAdd(gr + 4, a0 * B2[0] * r5);
        atomicAdd(gr + 5, a0 * B2[1] * r5);
        atomicAdd(gr + 6, a0 * B2[2] * r5);
        atomicAdd(gr + 7, a0 * B2[3] * r5);
        atomicAdd(gr + 8, a0 * B2[4] * r5);
        atomicAdd(gr + 9,  A1[0] * r3);
        atomicAdd(gr + 10, A1[1] * r3);
        atomicAdd(gr + 11, A1[2] * r3);
        atomicAdd(gr + 12, -r3 * (A1[0] * B1[0] + A1[1] * B1[1] + A1[2] * B1[2]));
        atomicAdd(gr + 13, -r6 * (A1[1] * B1[2] - A1[2] * B1[1]));
        atomicAdd(gr + 14, -r6 * (A1[2] * B1[0] - A1[0] * B1[2]));
        atomicAdd(gr + 15, -r6 * (A1[0] * B1[1] - A1[1] * B1[0]));
        atomicAdd(gr + 16, r10 * (A1[0] * B1[2] + A1[2] * B1[0]));
        atomicAdd(gr + 17, r10 * (A1[0] * B1[1] + A1[1] * B1[0]));
        atomicAdd(gr + 18, s30 * (2.f * A1[1] * B1[1] - A1[0] * B1[0] - A1[2] * B1[2]));
        atomicAdd(gr + 19, r10 * (A1[1] * B1[2] + A1[2] * B1[1]));
        atomicAdd(gr + 20, r10 * (A1[2] * B1[2] - A1[0] * B1[0]));
        {
            float Byy = -B2[2] * q6 - B2[4] * r2c;
            float Bzz = 2.f * B2[2] * q6;
            float Bxx = -B2[2] * q6 + B2[4] * r2c;
            float Bxy = B2[0] * r2c;
            float Byz = B2[1] * r2c;
            float Bxz = B2[3] * r2c;
            atomicAdd(gr + 21, -r5 * (Byy * A1[0] + Byz * A1[1] + Bxy * A1[2]));
            atomicAdd(gr + 22, -r5 * (Byz * A1[0] + Bzz * A1[1] + Bxz * A1[2]));
            atomicAdd(gr + 23, -r5 * (Bxy * A1[0] + Bxz * A1[1] + Bxx * A1[2]));
        }
        atomicAdd(gr + 24, -s30 * (B2[1] * A1[0] - B2[3] * A1[2] + 2.f * B2[4] * A1[1]));
        atomicAdd(gr + 25, -s30 * (-B2[0] * A1[0] - rt3 * B2[2] * A1[2] + B2[3] * A1[1] - B2[4] * A1[2]));
        atomicAdd(gr + 26, -s30 * (rt3 * B2[1] * A1[2] - rt3 * B2[3] * A1[0]));
        atomicAdd(gr + 27, -s30 * (B2[0] * A1[2] - B2[1] * A1[1] + rt3 * B2[2] * A1[0] - B2[4] * A1[0]));
        atomicAdd(gr + 28, -s30 * (-2.f * B2[0] * A1[1] + B2[1] * A1[2] + B2[3] * A1[0]));
        atomicAdd(gr + 29, A2[0] * r5);
        atomicAdd(gr + 30, A2[1] * r5);
        atomicAdd(gr + 31, A2[2] * r5);
        atomicAdd(gr + 32, A2[3] * r5);
        atomicAdd(gr + 33, A2[4] * r5);
        {
            float Ayy = -A2[2] * q6 - A2[4] * r2c;
            float Azz = 2.f * A2[2] * q6;
            float Axx = -A2[2] * q6 + A2[4] * r2c;
            float Axy = A2[0] * r2c;
            float Ayz = A2[1] * r2c;
            float Axz = A2[3] * r2c;
            atomicAdd(gr + 34, -r5 * (Ayy * B1[0] + Ayz * B1[1] + Axy * B1[2]));
            atomicAdd(gr + 35, -r5 * (Ayz * B1[0] + Azz * B1[1] + Axz * B1[2]));
            atomicAdd(gr + 36, -r5 * (Axy * B1[0] + Axz * B1[1] + Axx * B1[2]));
        }
        atomicAdd(gr + 37, s30 * (A2[1] * B1[0] - A2[3] * B1[2] + 2.f * A2[4] * B1[1]));
        atomicAdd(gr + 38, s30 * (-A2[0] * B1[0] - rt3 * A2[2] * B1[2] + A2[3] * B1[1] - A2[4] * B1[2]));
        atomicAdd(gr + 39, s30 * (rt3 * A2[1] * B1[2] - rt3 * A2[3] * B1[0]));
        atomicAdd(gr + 40, s30 * (A2[0] * B1[2] - A2[1] * B1[1] + rt3 * A2[2] * B1[0] - A2[4] * B1[0]));
        atomicAdd(gr + 41, s30 * (-2.f * A2[0] * B1[1] + A2[1] * B1[2] + A2[3] * B1[0]));
        atomicAdd(gr + 42, r5 * (A2[0] * B2[0] + A2[1] * B2[1] + A2[2] * B2[2] +
                                 A2[3] * B2[3] + A2[4] * B2[4]));
        atomicAdd(gr + 43, s30 * (-A2[0] * B2[1] + A2[1] * B2[0] +
                                  rt3 * (A2[2] * B2[3] - A2[3] * B2[2]) +
                                  A2[3] * B2[4] - A2[4] * B2[3]));
        atomicAdd(gr + 44, s30 * (-2.f * A2[0] * B2[4] + 2.f * A2[4] * B2[0] -
                                  A2[1] * B2[3] + A2[3] * B2[1]));
        atomicAdd(gr + 45, s30 * (A2[0] * B2[3] - A2[3] * B2[0] +
                                  rt3 * (A2[1] * B2[2] - A2[2] * B2[1]) +
                                  A2[1] * B2[4] - A2[4] * B2[1]));
        atomicAdd(gr + 46, -c222 * (-q6 * (A2[0] * B2[2] + A2[2] * B2[0]) +
                                    h2 * (A2[1] * B2[3] + A2[3] * B2[1])));
        atomicAdd(gr + 47, -c222 * (h6 * (A2[1] * B2[2] + A2[2] * B2[1]) -
                                    h2 * (A2[1] * B2[4] + A2[4] * B2[1]) +
                                    h2 * (A2[0] * B2[3] + A2[3] * B2[0])));
        atomicAdd(gr + 48, -c222 * (q6 * (A2[2] * B2[2] - A2[0] * B2[0] - A2[4] * B2[4]) +
                                    h6 * (A2[1] * B2[1] + A2[3] * B2[3])));
        atomicAdd(gr + 49, -c222 * (h6 * (A2[3] * B2[2] + A2[2] * B2[3]) +
                                    h2 * (A2[3] * B2[4] + A2[4] * B2[3]) +
                                    h2 * (A2[0] * B2[1] + A2[1] * B2[0])));
        atomicAdd(gr + 50, -c222 * (-q6 * (A2[4] * B2[2] + A2[2] * B2[4]) +
                                    h2 * (A2[3] * B2[3] - A2[1] * B2[1])));
    }
    __syncthreads();

    // Phase 2: per output j, contract with W1 (alpha*4*inv_nn folded), bf16 out.
    int j = t;
    if (j >= 368) return;
    if (j < 64) {
        int w = j;
        for (int r2 = 0; r2 < 8; r2++) {
            const float* Gn = Gl + r2 * 816;
            float acc = 0.f;
            for (int q = 0; q < 16; q++) {
                const float* gq = Gn + q * 51;
                acc += gq[0]  * lw[q * 64 + w]
                     + gq[12] * lw[2048 + q * 64 + w]
                     + gq[42] * lw[5248 + q * 64 + w];
            }
            mid16[(size_t)(blockIdx.x * 8 + r2) * 368 + j] =
                __float2bfloat16(0.33333333333333333f * acc);
        }
    } else if (j < 136) {
        int tt = j - 64, w = tt / 3, k = tt - 3 * w;
        for (int r2 = 0; r2 < 8; r2++) {
            const float* Gn = Gl + r2 * 816;
            float acc = 0.f;
            for (int q = 0; q < 16; q++) {
                const float* gq = Gn + q * 51;
                acc += gq[13 + k] * lw[3072 + q * 24 + w]
                     + gq[43 + k] * lw[6272 + q * 24 + w];
            }
            mid16[(size_t)(blockIdx.x * 8 + r2) * 368 + j] =
                __float2bfloat16(0.70710678118654752f * acc);
        }
    } else if (j < 208) {
        int tt = j - 136, w = tt / 3, k = tt - 3 * w;
        for (int r2 = 0; r2 < 8; r2++) {
            const float* Gn = Gl + r2 * 816;
            float acc = 0.f;
            for (int q = 0; q < 16; q++) {
                const float* gq = Gn + q * 51;
                acc += gq[1 + k]  * lw[1024 + q * 24 + w]
                     + gq[9 + k]  * lw[1664 + q * 24 + w]
                     + gq[21 + k] * lw[3712 + q * 24 + w]
                     + gq[34 + k] * lw[4608 + q * 24 + w];
            }
            mid16[(size_t)(blockIdx.x * 8 + r2) * 368 + j] =
                __float2bfloat16(0.5f * acc);
        }
    } else if (j < 288) {
        int tt = j - 208, w = tt / 5, k = tt - 5 * w;
        for (int r2 = 0; r2 < 8; r2++) {
            const float* Gn = Gl + r2 * 816;
            float acc = 0.f;
            for (int q = 0; q < 16; q++) {
                const float* gq = Gn + q * 51;
                acc += gq[4 + k]  * lw[1408 + q * 16 + w]
                     + gq[16 + k] * lw[3456 + q * 16 + w]
                     + gq[29 + k] * lw[4352 + q * 16 + w]
                     + gq[46 + k] * lw[6656 + q * 16 + w];
            }
            mid16[(size_t)(blockIdx.x * 8 + r2) * 368 + j] =
                __float2bfloat16(0.64549722436790280f * acc);
        }
    } else {
        int tt = j - 288, w = tt / 5, k = tt - 5 * w;
        for (int r2 = 0; r2 < 8; r2++) {
            const float* Gn = Gl + r2 * 816;
            float acc = 0.f;
            for (int q = 0; q < 16; q++) {
                const float* gq = Gn + q * 51;
                acc += gq[24 + k] * lw[4096 + q * 16 + w]
                     + gq[37 + k] * lw[4992 + q * 16 + w];
            }
            mid16[(size_t)(blockIdx.x * 8 + r2) * 368 + j] =
                __float2bfloat16(0.91287092917527690f * acc);
        }
    }
}

// --------------- fused TP2 + graph reduce (wave per node) ------------------
// R6-verified: permuted LDS W2 [w][q][u], coefs folded, bf16 mid gather.
__global__ __launch_bounds__(512) void k_out(const float* __restrict__ pos,
                                             const int* __restrict__ batch,
                                             const int* __restrict__ start,
                                             const int* __restrict__ csr,
                                             const __hip_bfloat16* __restrict__ mid16,
                                             const float* __restrict__ w2,
                                             float* __restrict__ out) {
    __shared__ float lw2[10624];
    {
        const float cT0f =  0.02830690f;
        const float cT1f = -0.02635231f;
        const float cT2f = -0.01634300f;
        const float cT3f =  0.01265893f;
        const float cT4f =  0.02041241f;
        for (int i = threadIdx.x; i < 10624; i += 512) {
            int src; float c;
            if (i < 6144) {            // T0 [w][q][u] <- (u*16+q)*6+w
                int w = i / 1024, r = i - 1024 * w;
                int q = r / 64, u = r - 64 * q;
                src = (u * 16 + q) * 6 + w; c = cT0f;
            } else if (i < 6528) {     // T1 [q][u]
                int t = i - 6144; int q = t / 24, u = t - 24 * q;
                src = 6144 + u * 16 + q; c = cT1f;
            } else if (i < 8832) {     // T2 [w][q][u]
                int t = i - 6528; int w = t / 384, r = t - 384 * w;
                int q = r / 24, u = r - 24 * q;
                src = 6528 + (u * 16 + q) * 6 + w; c = cT2f;
            } else if (i < 10368) {    // T3 [w][q][u]
                int t = i - 8832; int w = t / 256, r = t - 256 * w;
                int q = r / 16, u = r - 16 * q;
                src = 8832 + (u * 16 + q) * 6 + w; c = cT3f;
            } else {                   // T4 [q][u]
                int t = i - 10368; int q = t / 16, u = t - 16 * q;
                src = 10368 + u * 16 + q; c = cT4f;
            }
            lw2[i] = w2[src] * c;
        }
    }
    __syncthreads();

    int wave = threadIdx.x >> 6;
    int lane = threadIdx.x & 63;
    int n = blockIdx.x * 8 + wave;
    float pdx = pos[3 * n], pdy = pos[3 * n + 1], pdz = pos[3 * n + 2];
    int s0 = start[n], s1 = start[n + 1];

    float p0[6] = {0.f, 0.f, 0.f, 0.f, 0.f, 0.f};   // T0, u = lane
    float pA[6] = {0.f, 0.f, 0.f, 0.f, 0.f, 0.f};   // T1/T2/T3 by lane range
    float pB = 0.f;                                  // T4, lanes 0..15

    for (int idx = s0; idx < s1; ++idx) {
        int pk = csr[idx];
        int s = pk & 0xFFFF;
        int q = pk >> 16;
        float x = pos[3 * s] - pdx;
        float y = pos[3 * s + 1] - pdy;
        float z = pos[3 * s + 2] - pdz;
        float B1[3], B2[5];
        sh_from_vec(x, y, z, B1, B2);
        const __hip_bfloat16* mrow = mid16 + (size_t)s * 368;
        int q64 = q * 64, q24 = q * 24, q16 = q * 16;

        // T0: u = lane; weights [w][q][u] stride-1 in lane
        {
            float m = __bfloat162float(mrow[lane]);
#pragma unroll
            for (int w = 0; w < 6; w++) p0[w] += m * lw2[w * 1024 + q64 + lane];
        }
        if (lane < 24) {            // T1
            const __hip_bfloat16* rp = mrow + 64 + 3 * lane;
            float dd = __bfloat162float(rp[0]) * B1[0] +
                       __bfloat162float(rp[1]) * B1[1] +
                       __bfloat162float(rp[2]) * B1[2];
            pA[0] += dd * lw2[6144 + q24 + lane];
        } else if (lane < 48) {     // T2
            int u = lane - 24;
            const __hip_bfloat16* rp = mrow + 136 + 3 * u;
            float dd = __bfloat162float(rp[0]) * B1[0] +
                       __bfloat162float(rp[1]) * B1[1] +
                       __bfloat162float(rp[2]) * B1[2];
#pragma unroll
            for (int w = 0; w < 6; w++) pA[w] += dd * lw2[6528 + w * 384 + q24 + u];
        } else {                    // T3
            int u = lane - 48;
            const __hip_bfloat16* rp = mrow + 208 + 5 * u;
            float dd = __bfloat162float(rp[0]) * B2[0] +
                       __bfloat162float(rp[1]) * B2[1] +
                       __bfloat162float(rp[2]) * B2[2] +
                       __bfloat162float(rp[3]) * B2[3] +
                       __bfloat162float(rp[4]) * B2[4];
#pragma unroll
            for (int w = 0; w < 6; w++) pA[w] += dd * lw2[8832 + w * 256 + q16 + u];
        }
        if (lane < 16) {            // T4
            const __hip_bfloat16* rp = mrow + 288 + 5 * lane;
            float dd = __bfloat162float(rp[0]) * B2[0] +
                       __bfloat162float(rp[1]) * B2[1] +
                       __bfloat162float(rp[2]) * B2[2] +
                       __bfloat162float(rp[3]) * B2[3] +
                       __bfloat162float(rp[4]) * B2[4];
            pB += dd * lw2[10368 + q16 + lane];
        }
    }

    float o0 = 0.f;
    float ov[6];
#pragma unroll
    for (int w = 0; w < 6; w++) ov[w] = p0[w];
    if (lane < 24) {
        o0 += pA[0];
    } else {
#pragma unroll
        for (int w = 0; w < 6; w++) ov[w] += pA[w];
    }
    if (lane < 16) o0 += pB;

#pragma unroll
    for (int off = 32; off > 0; off >>= 1) {
        o0 += __shfl_down(o0, off, 64);
#pragma unroll
        for (int w = 0; w < 6; w++) ov[w] += __shfl_down(ov[w], off, 64);
    }
    if (lane == 0) {
        float* og = out + batch[n] * 7;
        atomicAdd(og + 0, o0);
#pragma unroll
        for (int w = 0; w < 6; w++) atomicAdd(og + 1 + w, ov[w]);
    }
}

// ---------------------------------------------------------------------------
extern "C" void kernel_launch(void* const* d_in, const int* in_sizes, int n_in,
                              void* d_out, int out_size, void* d_ws, size_t ws_size,
                              hipStream_t stream) {
    const float* pos  = (const float*)d_in[0];
    const int*   z    = (const int*)d_in[1];
    const int*   bat  = (const int*)d_in[2];
    const int*   esrc = (const int*)d_in[3];
    const int*   edst = (const int*)d_in[4];
    const float* w1   = (const float*)d_in[5];
    const float* w2   = (const float*)d_in[6];
    float* out = (float*)d_out;

    int*   wsI = (int*)d_ws;
    float* wsF = (float*)d_ws;
    int* counts = wsI + 0;
    int* start  = wsI + 32768;
    int* cursor = wsI + 65536;
    int* csr    = wsI + 98304;
    float* node_sh = wsF + 524288;
    __hip_bfloat16* mid16 = (__hip_bfloat16*)(wsF + 1048576);

    k_zero<<<64, 256, 0, stream>>>(counts, out);
    k_hist<<<(N_EDGES + 255) / 256, 256, 0, stream>>>(edst, counts);
    k_scan<<<1, 1024, 0, stream>>>(counts, start, cursor);
    k_fill<<<(N_EDGES + 255) / 256, 256, 0, stream>>>(esrc, edst, z, cursor, csr);
    k_nodesh<<<NN_NODES / 4, 256, 0, stream>>>(pos, start, csr, node_sh);
    k_mid<<<NN_NODES / 8, 384, 0, stream>>>(pos, node_sh, start, csr, w1, mid16);
    k_out<<<NN_NODES / 8, 512, 0, stream>>>(pos, bat, start, csr, mid16, w2, out);
}